// Round 2
// baseline (340.219 us; speedup 1.0000x reference)
//
#include <hip/hip_runtime.h>

typedef short  s16x8 __attribute__((ext_vector_type(8)));   // 8 bf16 bit patterns
typedef float  f32x4 __attribute__((ext_vector_type(4)));
typedef unsigned int u32;
typedef unsigned int u32x4 __attribute__((ext_vector_type(4)));
typedef unsigned short u16;

#define DEVI static __device__ __forceinline__

constexpr int T_  = 128;
constexpr int F_  = 14;
constexpr int H_  = 64;
constexpr int BPW = 16;   // batch rows per wave
constexpr int HP  = 68;   // fc-head LDS row pitch (floats)

DEVI u16 f2bf(float f) {                     // RNE, used for weights (one-time)
  u32 u = __builtin_bit_cast(u32, f);
  u += 0x7fffu + ((u >> 16) & 1u);
  return (u16)(u >> 16);
}
DEVI u16 f2bfF(float f) {                    // round-half-up, in-loop (cheap: add+shift)
  u32 u = __builtin_bit_cast(u32, f);
  return (u16)((u + 0x8000u) >> 16);
}
DEVI u32 pkbf(float a, float b) {            // pack 2 bf16 into one dword
  u32 ua = __builtin_bit_cast(u32, a) + 0x8000u;
  u32 ub = __builtin_bit_cast(u32, b) + 0x8000u;
  return (ua >> 16) | (ub & 0xffff0000u);
}
// B-frag kt from tanh'd acc tiles: elements 0-3 = tile kt, 4-7 = tile kt+2
DEVI s16x8 packfrag(const f32x4& a, const f32x4& b) {
  u32x4 p;
  p[0] = pkbf(a[0], a[1]); p[1] = pkbf(a[2], a[3]);
  p[2] = pkbf(b[0], b[1]); p[3] = pkbf(b[2], b[3]);
  return __builtin_bit_cast(s16x8, p);
}
DEVI float tanhfast(float x) {
  // tanh(x) = 2/(1+2^(-2*log2e*x)) - 1 ; safe for |x| < ~44
  float e = exp2f(x * -2.8853900817779268f);
  float r = __builtin_amdgcn_rcpf(1.0f + e);
  return __builtin_fmaf(2.0f, r, -1.0f);
}
DEVI f32x4 tanh4(const f32x4& v) {
  f32x4 r;
  r[0] = tanhfast(v[0]); r[1] = tanhfast(v[1]);
  r[2] = tanhfast(v[2]); r[3] = tanhfast(v[3]);
  return r;
}
DEVI f32x4 MFMA(s16x8 a, s16x8 b, f32x4 c) {
  return __builtin_amdgcn_mfma_f32_16x16x32_bf16(a, b, c, 0, 0, 0);
}
// 8 contiguous fp32 (16B-aligned) -> bf16 A-frag
DEVI s16x8 ldrow8(const float* p) {
  const f32x4 a = ((const f32x4*)p)[0];
  const f32x4 b = ((const f32x4*)p)[1];
  s16x8 r;
  r[0] = (short)f2bf(a[0]); r[1] = (short)f2bf(a[1]);
  r[2] = (short)f2bf(a[2]); r[3] = (short)f2bf(a[3]);
  r[4] = (short)f2bf(b[0]); r[5] = (short)f2bf(b[1]);
  r[6] = (short)f2bf(b[2]); r[7] = (short)f2bf(b[3]);
  return r;
}

__global__ __launch_bounds__(64, 1) void rnn_wave(
    const float* __restrict__ x,
    const float* __restrict__ Wih0, const float* __restrict__ Whh0,
    const float* __restrict__ bih0, const float* __restrict__ bhh0,
    const float* __restrict__ Wih1, const float* __restrict__ Whh1,
    const float* __restrict__ bih1, const float* __restrict__ bhh1,
    const float* __restrict__ Wih2, const float* __restrict__ Whh2,
    const float* __restrict__ bih2, const float* __restrict__ bhh2,
    const float* __restrict__ fc1w, const float* __restrict__ fc1b,
    const float* __restrict__ fc2w, const float* __restrict__ fc2b,
    float* __restrict__ out)
{
  __shared__ __align__(16) float h2l[BPW][HP];   // fc-head scratch only

  const int lane = threadIdx.x & 63;
  const int g    = lane >> 4;       // k-group / D-row group
  const int m    = lane & 15;       // batch column
  const int b0   = blockIdx.x * BPW;

  // ---- weights as A-frags, rows permuted: tile n, tile-row rho -> logical hid
  //      L(n,rho) = 32*(n&1) + 8*(rho>>2) + 4*(n>>1) + (rho&3)
  // K-side (columns) stays natural order, so h state is in natural order.
  s16x8 A0x[4], A0h[4][2], A1i[4][2], A1h[4][2], A2i[4][2], A2h[4][2];
  f32x4 bc0[4], bc1[4], bc2[4];

  #pragma unroll
  for (int n = 0; n < 4; n++) {
    const int Lr = 32 * (n & 1) + 8 * (m >> 2) + 4 * (n >> 1) + (m & 3);
    { // layer0 x-part: k = 8g+j, valid k < 14, zero pad to 32
      s16x8 r;
      #pragma unroll
      for (int j2 = 0; j2 < 8; j2++) {
        const int kk = 8 * g + j2;
        r[j2] = (kk < F_) ? (short)f2bf(Wih0[Lr * F_ + kk]) : (short)0;
      }
      A0x[n] = r;
    }
    #pragma unroll
    for (int kt = 0; kt < 2; kt++) {
      const int ko = 32 * kt + 8 * g;
      A0h[n][kt] = ldrow8(Whh0 + Lr * H_ + ko);
      A1i[n][kt] = ldrow8(Wih1 + Lr * H_ + ko);
      A1h[n][kt] = ldrow8(Whh1 + Lr * H_ + ko);
      A2i[n][kt] = ldrow8(Wih2 + Lr * H_ + ko);
      A2h[n][kt] = ldrow8(Whh2 + Lr * H_ + ko);
    }
    { // biases: acc reg r <-> logical row Lb+r (Lb multiple of 4 -> aligned f32x4)
      const int Lb = 32 * (n & 1) + 8 * g + 4 * (n >> 1);
      bc0[n] = *(const f32x4*)(bih0 + Lb) + *(const f32x4*)(bhh0 + Lb);
      bc1[n] = *(const f32x4*)(bih1 + Lb) + *(const f32x4*)(bhh1 + Lb);
      bc2[n] = *(const f32x4*)(bih2 + Lb) + *(const f32x4*)(bhh2 + Lb);
    }
  }

  // ---- h-state frags (natural k order), zero init
  s16x8 F0[2], F1[2], F2[2];
  #pragma unroll
  for (int kt = 0; kt < 2; kt++) {
    s16x8 z;
    #pragma unroll
    for (int i = 0; i < 8; i++) z[i] = 0;
    F0[kt] = z; F1[kt] = z; F2[kt] = z;
  }

  const float* xrow = x + (size_t)(b0 + m) * T_ * F_;
  auto load_x = [&](int t) -> s16x8 {   // B-frag: x[batch m][k=8g+j], pad >=14 with 0
    s16x8 r;
    const float* p = xrow + t * F_;
    if (g == 0) {
      #pragma unroll
      for (int i = 0; i < 8; i++) r[i] = (short)f2bfF(p[i]);
    } else if (g == 1) {
      #pragma unroll
      for (int i = 0; i < 6; i++) r[i] = (short)f2bfF(p[8 + i]);
      r[6] = 0; r[7] = 0;
    } else {
      #pragma unroll
      for (int i = 0; i < 8; i++) r[i] = 0;
    }
    return r;
  };

  s16x8 bx = load_x(0);
  f32x4 h2v[4];

  #pragma unroll 1
  for (int t = 0; t < T_; t++) {
    s16x8 bxn = load_x(t + 1 < T_ ? t + 1 : T_ - 1);  // prefetch next step

    f32x4 a0[4], a1[4], a2[4];
    // phase 0: everything that depends only on previous-step state (28 MFMAs)
    #pragma unroll
    for (int n = 0; n < 4; n++) {
      f32x4 a = bc0[n];
      a = MFMA(A0x[n], bx, a);
      a = MFMA(A0h[n][0], F0[0], a);
      a = MFMA(A0h[n][1], F0[1], a);
      a0[n] = a;
    }
    #pragma unroll
    for (int n = 0; n < 4; n++) {
      f32x4 a = bc1[n];
      a = MFMA(A1h[n][0], F1[0], a);
      a = MFMA(A1h[n][1], F1[1], a);
      a1[n] = a;
    }
    #pragma unroll
    for (int n = 0; n < 4; n++) {
      f32x4 a = bc2[n];
      a = MFMA(A2h[n][0], F2[0], a);
      a = MFMA(A2h[n][1], F2[1], a);
      a2[n] = a;
    }

    // layer 0 activation -> feeds layer 1 (D->B is pure register re-pack)
    f32x4 hv[4];
    #pragma unroll
    for (int n = 0; n < 4; n++) hv[n] = tanh4(a0[n]);
    F0[0] = packfrag(hv[0], hv[2]);
    F0[1] = packfrag(hv[1], hv[3]);
    #pragma unroll
    for (int n = 0; n < 4; n++) {
      a1[n] = MFMA(A1i[n][0], F0[0], a1[n]);
      a1[n] = MFMA(A1i[n][1], F0[1], a1[n]);
    }

    // layer 1 activation -> feeds layer 2
    #pragma unroll
    for (int n = 0; n < 4; n++) hv[n] = tanh4(a1[n]);
    F1[0] = packfrag(hv[0], hv[2]);
    F1[1] = packfrag(hv[1], hv[3]);
    #pragma unroll
    for (int n = 0; n < 4; n++) {
      a2[n] = MFMA(A2i[n][0], F1[0], a2[n]);
      a2[n] = MFMA(A2i[n][1], F1[1], a2[n]);
    }

    // layer 2 activation (kept fp32 for the fc head)
    #pragma unroll
    for (int n = 0; n < 4; n++) h2v[n] = tanh4(a2[n]);
    F2[0] = packfrag(h2v[0], h2v[2]);
    F2[1] = packfrag(h2v[1], h2v[3]);

    bx = bxn;
  }

  // ---- FC head: un-permute h2 through LDS (one-time), then dot products
  #pragma unroll
  for (int n = 0; n < 4; n++) {
    const int Lb = 32 * (n & 1) + 8 * g + 4 * (n >> 1);
    *(f32x4*)&h2l[m][Lb] = h2v[n];
  }
  __syncthreads();

  float hr[64];
  #pragma unroll
  for (int q = 0; q < 16; q++) {
    f32x4 v = *(const f32x4*)&h2l[m][4 * q];
    hr[4 * q + 0] = v[0]; hr[4 * q + 1] = v[1];
    hr[4 * q + 2] = v[2]; hr[4 * q + 3] = v[3];
  }
  float acc2 = 0.f;
  #pragma unroll
  for (int jj = 0; jj < 8; jj++) {
    const int jf = 8 * g + jj;
    float s = fc1b[jf];
    const f32x4* wp = (const f32x4*)(fc1w + jf * H_);
    #pragma unroll
    for (int kq = 0; kq < 16; kq++) {
      f32x4 wv = wp[kq];
      s += hr[4 * kq + 0] * wv[0] + hr[4 * kq + 1] * wv[1]
         + hr[4 * kq + 2] * wv[2] + hr[4 * kq + 3] * wv[3];
    }
    s = fmaxf(s, 0.f);
    acc2 += s * fc2w[jf];
  }
  acc2 += __shfl_xor(acc2, 16, 64);
  acc2 += __shfl_xor(acc2, 32, 64);
  if (lane < 16) out[b0 + m] = acc2 + fc2b[0];
}

extern "C" void kernel_launch(void* const* d_in, const int* in_sizes, int n_in,
                              void* d_out, int out_size, void* d_ws, size_t ws_size,
                              hipStream_t stream) {
  const float* x    = (const float*)d_in[0];
  const float* Wih0 = (const float*)d_in[1];
  const float* Whh0 = (const float*)d_in[2];
  const float* bih0 = (const float*)d_in[3];
  const float* bhh0 = (const float*)d_in[4];
  const float* Wih1 = (const float*)d_in[5];
  const float* Whh1 = (const float*)d_in[6];
  const float* bih1 = (const float*)d_in[7];
  const float* bhh1 = (const float*)d_in[8];
  const float* Wih2 = (const float*)d_in[9];
  const float* Whh2 = (const float*)d_in[10];
  const float* bih2 = (const float*)d_in[11];
  const float* bhh2 = (const float*)d_in[12];
  const float* fc1w = (const float*)d_in[13];
  const float* fc1b = (const float*)d_in[14];
  const float* fc2w = (const float*)d_in[15];
  const float* fc2b = (const float*)d_in[16];

  rnn_wave<<<dim3(4096 / BPW), dim3(64), 0, stream>>>(
      x, Wih0, Whh0, bih0, bhh0, Wih1, Whh1, bih1, bhh1,
      Wih2, Whh2, bih2, bhh2, fc1w, fc1b, fc2w, fc2b, (float*)d_out);
}

// Round 3
// 279.714 us; speedup vs baseline: 1.2163x; 1.2163x over previous
//
#include <hip/hip_runtime.h>

typedef short  s16x8 __attribute__((ext_vector_type(8)));   // 8 bf16 bit patterns
typedef float  f32x4 __attribute__((ext_vector_type(4)));
typedef unsigned int u32;
typedef unsigned int u32x4 __attribute__((ext_vector_type(4)));
typedef unsigned short u16;

#define DEVI static __device__ __forceinline__

constexpr int T_  = 128;
constexpr int F_  = 14;
constexpr int H_  = 64;
constexpr int BPW = 16;   // batch rows per block (both waves share them, split hidden)
constexpr int HP  = 68;   // fc-head LDS row pitch (floats)

DEVI u16 f2bf(float f) {                     // RNE, one-time weight convert
  u32 u = __builtin_bit_cast(u32, f);
  u += 0x7fffu + ((u >> 16) & 1u);
  return (u16)(u >> 16);
}
DEVI u16 f2bfF(float f) {                    // round-half-up, in-loop (add+shift)
  u32 u = __builtin_bit_cast(u32, f);
  return (u16)((u + 0x8000u) >> 16);
}
DEVI u32 pkbf(float a, float b) {            // pack 2 bf16 into one dword
  u32 ua = __builtin_bit_cast(u32, a) + 0x8000u;
  u32 ub = __builtin_bit_cast(u32, b) + 0x8000u;
  return (ua >> 16) | (ub & 0xffff0000u);
}
DEVI float tanhfast(float x) {
  // tanh(x) = 2/(1+2^(-2*log2e*x)) - 1 ; safe for |x| < ~44
  float e = exp2f(x * -2.8853900817779268f);
  float r = __builtin_amdgcn_rcpf(1.0f + e);
  return __builtin_fmaf(2.0f, r, -1.0f);
}
DEVI f32x4 tanh4(const f32x4& v) {
  f32x4 r;
  r[0] = tanhfast(v[0]); r[1] = tanhfast(v[1]);
  r[2] = tanhfast(v[2]); r[3] = tanhfast(v[3]);
  return r;
}
DEVI f32x4 MFMA(s16x8 a, s16x8 b, f32x4 c) {
  return __builtin_amdgcn_mfma_f32_16x16x32_bf16(a, b, c, 0, 0, 0);
}
// 8 contiguous fp32 (16B-aligned) -> bf16 A-frag
DEVI s16x8 ldrow8(const float* p) {
  const f32x4 a = ((const f32x4*)p)[0];
  const f32x4 b = ((const f32x4*)p)[1];
  s16x8 r;
  r[0] = (short)f2bf(a[0]); r[1] = (short)f2bf(a[1]);
  r[2] = (short)f2bf(a[2]); r[3] = (short)f2bf(a[3]);
  r[4] = (short)f2bf(b[0]); r[5] = (short)f2bf(b[1]);
  r[6] = (short)f2bf(b[2]); r[7] = (short)f2bf(b[3]);
  return r;
}

// 2 waves per block share 16 batch rows and split the hidden dim.
// Permutation: logical hid L(w,tau,g_or_rho) = 32*tau + 8*(rho>>2) + 4*w + (rho&3)
//  - wave w, local tile tau: acc reg r at lane (g,m) holds logical row 32*tau+8*g+4*w+r
//  - B-frag tau at lane (g,m) element j corresponds to logical k = 32*tau + 8*g + j
//  => wave w's packed pair fills j = 4w..4w+3 of the SAME lane's frag tau;
//     the partner wave supplies the other 4 — a lane-symmetric 16B LDS exchange.
__global__ __launch_bounds__(128, 1) void rnn_2w(
    const float* __restrict__ x,
    const float* __restrict__ Wih0, const float* __restrict__ Whh0,
    const float* __restrict__ bih0, const float* __restrict__ bhh0,
    const float* __restrict__ Wih1, const float* __restrict__ Whh1,
    const float* __restrict__ bih1, const float* __restrict__ bhh1,
    const float* __restrict__ Wih2, const float* __restrict__ Whh2,
    const float* __restrict__ bih2, const float* __restrict__ bhh2,
    const float* __restrict__ fc1w, const float* __restrict__ fc1b,
    const float* __restrict__ fc2w, const float* __restrict__ fc2b,
    float* __restrict__ out)
{
  __shared__ __align__(16) u32x4 xch[3][2][64];   // [layer-slot][wave][lane], 16B/lane
  __shared__ __align__(16) float h2l[BPW][HP];    // fc-head scratch

  const int tid  = threadIdx.x;
  const int w    = tid >> 6;        // wave id: hidden half
  const int lane = tid & 63;
  const int g    = lane >> 4;
  const int m    = lane & 15;
  const int b0   = blockIdx.x * BPW;

  // ---- weights as A-frags (per wave: 22 frags = 88 VGPRs) ----
  s16x8 A0x[2], A0h[2][2], A1i[2][2], A1h[2][2], A2i[2][2], A2h[2][2];
  f32x4 bc0[2], bc1[2], bc2[2];
  #pragma unroll
  for (int tau = 0; tau < 2; tau++) {
    const int Lr = 32 * tau + 8 * (m >> 2) + 4 * w + (m & 3);
    { // layer0 x-part: k = 8g+j, valid k < 14, zero pad to 32
      s16x8 r;
      #pragma unroll
      for (int j2 = 0; j2 < 8; j2++) {
        const int kk = 8 * g + j2;
        r[j2] = (kk < F_) ? (short)f2bf(Wih0[Lr * F_ + kk]) : (short)0;
      }
      A0x[tau] = r;
    }
    #pragma unroll
    for (int kt = 0; kt < 2; kt++) {
      const int ko = 32 * kt + 8 * g;
      A0h[tau][kt] = ldrow8(Whh0 + Lr * H_ + ko);
      A1i[tau][kt] = ldrow8(Wih1 + Lr * H_ + ko);
      A1h[tau][kt] = ldrow8(Whh1 + Lr * H_ + ko);
      A2i[tau][kt] = ldrow8(Wih2 + Lr * H_ + ko);
      A2h[tau][kt] = ldrow8(Whh2 + Lr * H_ + ko);
    }
    const int Lb = 32 * tau + 8 * g + 4 * w;   // acc reg r <-> logical row Lb+r
    bc0[tau] = *(const f32x4*)(bih0 + Lb) + *(const f32x4*)(bhh0 + Lb);
    bc1[tau] = *(const f32x4*)(bih1 + Lb) + *(const f32x4*)(bhh1 + Lb);
    bc2[tau] = *(const f32x4*)(bih2 + Lb) + *(const f32x4*)(bhh2 + Lb);
  }

  // ---- full h-state frags (merged own+partner each step), zero init ----
  s16x8 F0[2], F1[2], F2[2];
  {
    s16x8 z;
    #pragma unroll
    for (int i = 0; i < 8; i++) z[i] = 0;
    F0[0] = z; F0[1] = z; F1[0] = z; F1[1] = z; F2[0] = z; F2[1] = z;
  }

  const float* xrow = x + (size_t)(b0 + m) * T_ * F_;
  auto load_x = [&](int t) -> s16x8 {   // B-frag: x[batch m][k=8g+j], pad >=14 with 0
    s16x8 r;
    const float* p = xrow + t * F_;
    if (g == 0) {
      #pragma unroll
      for (int i = 0; i < 8; i++) r[i] = (short)f2bfF(p[i]);
    } else if (g == 1) {
      #pragma unroll
      for (int i = 0; i < 6; i++) r[i] = (short)f2bfF(p[8 + i]);
      r[6] = 0; r[7] = 0;
    } else {
      #pragma unroll
      for (int i = 0; i < 8; i++) r[i] = 0;
    }
    return r;
  };

  // pack own halves, exchange with partner wave, merge into full B-frags
  auto xchg = [&](int slot, const f32x4& h0, const f32x4& h1, s16x8* F) {
    u32x4 v;
    v[0] = pkbf(h0[0], h0[1]); v[1] = pkbf(h0[2], h0[3]);
    v[2] = pkbf(h1[0], h1[1]); v[3] = pkbf(h1[2], h1[3]);
    xch[slot][w][lane] = v;                 // ds_write_b128, stride 16B -> conflict-free
    __syncthreads();
    u32x4 p = xch[slot][w ^ 1][lane];       // ds_read_b128, conflict-free
    u32x4 f0, f1;
    if (w == 0) {
      f0[0] = v[0]; f0[1] = v[1]; f0[2] = p[0]; f0[3] = p[1];
      f1[0] = v[2]; f1[1] = v[3]; f1[2] = p[2]; f1[3] = p[3];
    } else {
      f0[0] = p[0]; f0[1] = p[1]; f0[2] = v[0]; f0[3] = v[1];
      f1[0] = p[2]; f1[1] = p[3]; f1[2] = v[2]; f1[3] = v[3];
    }
    F[0] = __builtin_bit_cast(s16x8, f0);
    F[1] = __builtin_bit_cast(s16x8, f1);
  };

  s16x8 bx = load_x(0);
  f32x4 h2a, h2b;

  #pragma unroll 1
  for (int t = 0; t < T_; t++) {
    s16x8 bxn = load_x(t + 1 < T_ ? t + 1 : T_ - 1);  // prefetch next step

    f32x4 a0[2], a1[2], a2[2];
    // phase 0: all MFMAs depending only on previous-step state (14 MFMAs)
    #pragma unroll
    for (int tau = 0; tau < 2; tau++) {
      f32x4 a = bc0[tau];
      a = MFMA(A0x[tau], bx, a);
      a = MFMA(A0h[tau][0], F0[0], a);
      a = MFMA(A0h[tau][1], F0[1], a);
      a0[tau] = a;
    }
    #pragma unroll
    for (int tau = 0; tau < 2; tau++) {
      f32x4 a = bc1[tau];
      a = MFMA(A1h[tau][0], F1[0], a);
      a = MFMA(A1h[tau][1], F1[1], a);
      a1[tau] = a;
      f32x4 b = bc2[tau];
      b = MFMA(A2h[tau][0], F2[0], b);
      b = MFMA(A2h[tau][1], F2[1], b);
      a2[tau] = b;
    }

    // layer 0 activation -> exchange -> layer 1 input MFMAs
    xchg(0, tanh4(a0[0]), tanh4(a0[1]), F0);
    #pragma unroll
    for (int tau = 0; tau < 2; tau++) {
      a1[tau] = MFMA(A1i[tau][0], F0[0], a1[tau]);
      a1[tau] = MFMA(A1i[tau][1], F0[1], a1[tau]);
    }

    // layer 1 activation -> exchange -> layer 2 input MFMAs
    xchg(1, tanh4(a1[0]), tanh4(a1[1]), F1);
    #pragma unroll
    for (int tau = 0; tau < 2; tau++) {
      a2[tau] = MFMA(A2i[tau][0], F1[0], a2[tau]);
      a2[tau] = MFMA(A2i[tau][1], F1[1], a2[tau]);
    }

    // layer 2 activation (fp32 kept for head) -> exchange
    h2a = tanh4(a2[0]); h2b = tanh4(a2[1]);
    xchg(2, h2a, h2b, F2);

    bx = bxn;
  }

  // ---- FC head: un-permute fp32 h2 halves through LDS, wave 0 computes ----
  *(f32x4*)&h2l[m][8 * g + 4 * w]      = h2a;   // tau=0 rows
  *(f32x4*)&h2l[m][32 + 8 * g + 4 * w] = h2b;   // tau=1 rows
  __syncthreads();

  if (w == 0) {
    float hr[64];
    #pragma unroll
    for (int q = 0; q < 16; q++) {
      f32x4 v = *(const f32x4*)&h2l[m][4 * q];
      hr[4 * q + 0] = v[0]; hr[4 * q + 1] = v[1];
      hr[4 * q + 2] = v[2]; hr[4 * q + 3] = v[3];
    }
    float acc2 = 0.f;
    #pragma unroll
    for (int jj = 0; jj < 8; jj++) {
      const int jf = 8 * g + jj;
      float s = fc1b[jf];
      const f32x4* wp = (const f32x4*)(fc1w + jf * H_);
      #pragma unroll
      for (int kq = 0; kq < 16; kq++) {
        f32x4 wv = wp[kq];
        s += hr[4 * kq + 0] * wv[0] + hr[4 * kq + 1] * wv[1]
           + hr[4 * kq + 2] * wv[2] + hr[4 * kq + 3] * wv[3];
      }
      s = fmaxf(s, 0.f);
      acc2 += s * fc2w[jf];
    }
    acc2 += __shfl_xor(acc2, 16, 64);
    acc2 += __shfl_xor(acc2, 32, 64);
    if (lane < 16) out[b0 + m] = acc2 + fc2b[0];
  }
}

extern "C" void kernel_launch(void* const* d_in, const int* in_sizes, int n_in,
                              void* d_out, int out_size, void* d_ws, size_t ws_size,
                              hipStream_t stream) {
  const float* x    = (const float*)d_in[0];
  const float* Wih0 = (const float*)d_in[1];
  const float* Whh0 = (const float*)d_in[2];
  const float* bih0 = (const float*)d_in[3];
  const float* bhh0 = (const float*)d_in[4];
  const float* Wih1 = (const float*)d_in[5];
  const float* Whh1 = (const float*)d_in[6];
  const float* bih1 = (const float*)d_in[7];
  const float* bhh1 = (const float*)d_in[8];
  const float* Wih2 = (const float*)d_in[9];
  const float* Whh2 = (const float*)d_in[10];
  const float* bih2 = (const float*)d_in[11];
  const float* bhh2 = (const float*)d_in[12];
  const float* fc1w = (const float*)d_in[13];
  const float* fc1b = (const float*)d_in[14];
  const float* fc2w = (const float*)d_in[15];
  const float* fc2b = (const float*)d_in[16];

  rnn_2w<<<dim3(4096 / BPW), dim3(128), 0, stream>>>(
      x, Wih0, Whh0, bih0, bhh0, Wih1, Whh1, bih1, bhh1,
      Wih2, Whh2, bih2, bhh2, fc1w, fc1b, fc2w, fc2b, (float*)d_out);
}